// Round 4
// baseline (351.262 us; speedup 1.0000x reference)
//
#include <hip/hip_runtime.h>
#include <stdint.h>

#define B_    32
#define D_    256
#define HW_   1024
#define N_    32768      // B_*HW_
#define K_    1024
#define BETA_ 0.25f
#define OUT0  8388608    // N_*D_

typedef short bf16x8 __attribute__((ext_vector_type(8)));
typedef short s16x4  __attribute__((ext_vector_type(4)));
typedef float f32x4  __attribute__((ext_vector_type(4)));

// ---- workspace layout (bytes) ----
#define E2_OFF    0          // 512 KB  bf16 of E, A-fragment order (k-major)
#define ENORM_OFF 524288     // 4 KB    ||e_k||^2 fp32 (exact, from fp32 e)
#define SUMED_OFF 528384     // 1 KB    col sums of E
#define SUMZD_OFF 529408     // 1 KB    per-d sums of Z
#define CNT_OFF   530432     // 4 KB    histogram
#define SCAL_OFF  534528     // 32 B    doubles: [1]=sum z^2, [2]=sum diff^2
#define ZERO_OFF  SUMED_OFF
#define ZERO_BYTES (534560 - SUMED_OFF)

__device__ __forceinline__ unsigned short f2bf(float f) {
  unsigned int u = __float_as_uint(f);
  u += 0x7FFFu + ((u >> 16) & 1u);          // round-to-nearest-even
  return (unsigned short)(u >> 16);
}

__device__ __forceinline__ unsigned long long pack64(float v, int k) {
  unsigned int b = __float_as_uint(v);
  b = (b & 0x80000000u) ? ~b : (b | 0x80000000u);   // order-preserving map
  return ((unsigned long long)b << 32) | (unsigned int)k;
}

__device__ __forceinline__ float unpack32(unsigned int p) {
  p = (p & 0x80000000u) ? (p ^ 0x80000000u) : ~p;
  return __uint_as_float(p);
}

__device__ __forceinline__ float blockReduceSum(float v, volatile float* sred) {
  #pragma unroll
  for (int off = 32; off > 0; off >>= 1) v += __shfl_down(v, off, 64);
  __syncthreads();
  if ((threadIdx.x & 63) == 0) sred[threadIdx.x >> 6] = v;
  __syncthreads();
  float r = 0.0f;
  if (threadIdx.x == 0) {
    const int nw = blockDim.x >> 6;
    for (int i = 0; i < nw; ++i) r += sred[i];
  }
  return r;  // valid on thread 0 only
}

// ---------------------------------------------------------------------------
// E prep: single-bf16 A-fragment-ordered E, enorm[k] (exact fp32), col sums.
// grid 64 x 512. Block kt handles codes [kt*16, kt*16+16).
// Fragment index: fi = (ktg*8 + ds)*64 + lane,  ktg = k/16, ds = d/32.
// lane -> (m=lane&15 = k%16, d = ds*32 + (lane>>4)*8 + j).
// ---------------------------------------------------------------------------
__global__ void vq_eprep(const float* __restrict__ e, unsigned short* __restrict__ E2,
                         float* __restrict__ enorm, float* __restrict__ sum_e_d) {
  __shared__ float ered[16][33];
  __shared__ float sumed[256];
  const int t  = threadIdx.x;
  const int kt = blockIdx.x;
  const int ds = t >> 6, l = t & 63;
  const int q  = l >> 4, m = l & 15;
  const int k  = kt * 16 + m;
  const int d0 = ds * 32 + q * 8;
  if (t < 256) sumed[t] = 0.0f;
  __syncthreads();

  const float* ep = e + (size_t)k * D_ + d0;
  const float4 v0 = *(const float4*)ep;
  const float4 v1 = *(const float4*)(ep + 4);
  const float vv[8] = {v0.x, v0.y, v0.z, v0.w, v1.x, v1.y, v1.z, v1.w};
  short hv[8];
  float p = 0.0f;
  #pragma unroll
  for (int j = 0; j < 8; ++j) {
    const float f = vv[j];
    p += f * f;
    hv[j] = (short)f2bf(f);
    atomicAdd(&sumed[d0 + j], f);
  }
  const size_t fi = ((size_t)(kt * 8 + ds)) * 64 + l;
  *(bf16x8*)(E2 + fi * 8) = *(bf16x8*)hv;

  ered[m][ds * 4 + q] = p;
  __syncthreads();
  if (t < 16) {
    float s = 0.0f;
    #pragma unroll
    for (int i = 0; i < 32; ++i) s += ered[t][i];
    enorm[kt * 16 + t] = s;
  }
  if (t < 256) atomicAdd(&sum_e_d[t], sumed[t]);
}

// ---------------------------------------------------------------------------
// Fused argmin + gather, single-term bf16.
// grid 512 (b x 16 hw-tiles of 64 n) x 512 thr, __launch_bounds__(512,4):
// acc[4][4] = 64 regs -> 4 waves/SIMD, 2 blocks/CU.
// Wave w covers k in {c*512 + w*64 .. +64} for chunk c = 0,1 (argmin folded
// between chunks so acc regs are reused). A-frags stream from L2 (512 KB/blk),
// B-frags (Z, single bf16) LDS-resident. Epilogue writes out in 2x32-n passes.
// ---------------------------------------------------------------------------
__global__ __launch_bounds__(512, 4)
void vq_argmin4(const float* __restrict__ z, const float* __restrict__ e,
                const unsigned short* __restrict__ E2,
                const float* __restrict__ enorm_g,
                float* __restrict__ out, unsigned int* __restrict__ counts,
                float* __restrict__ sum_z_d, double* __restrict__ scald) {
  union SM {
    unsigned short Zh[8][2048];     // 32768 B: [ds][slot*8+j]
    float erow[32 * 257];           // 32896 B (epilogue staging, 32 n / pass)
  };
  __shared__ SM sm;
  __shared__ float en[1024];
  __shared__ unsigned long long red[8][64];
  __shared__ float sumzd[256];
  __shared__ float zn2[64];
  __shared__ unsigned int kbuf[64];

  const int t  = threadIdx.x;
  const int nt = blockIdx.x;
  const int b   = nt >> 4;
  const int hw0 = (nt & 15) << 6;
  const int w = t >> 6, l = t & 63;
  const int quad = l >> 4;

  // staging identity
  const int slot  = t & 255;
  const int jh    = t >> 8;                            // 0/1 -> j = jh*4 + c
  const int squad = (slot >> 4) & 3;
  const int nloc  = ((slot >> 6) << 4) + (slot & 15);  // ni*16 + n15
  const float* zb = z + (size_t)b * D_ * HW_ + hw0 + nloc;

  if (t < 256) sumzd[t] = 0.0f;
  if (t < 64)  zn2[t] = 0.0f;
  en[t] = enorm_g[t];
  en[t + 512] = enorm_g[t + 512];
  __syncthreads();

  // ---- Phase A: stage all of Z (single bf16) + exact fp32 stats ----
  float zn2acc = 0.0f;
  #pragma unroll
  for (int ds = 0; ds < 8; ++ds) {
    const int dbase = ds * 32 + squad * 8 + jh * 4;
    float f[4];
    #pragma unroll
    for (int c = 0; c < 4; ++c) f[c] = zb[(size_t)(dbase + c) * HW_];
    short hv[4];
    #pragma unroll
    for (int c = 0; c < 4; ++c) {
      zn2acc = fmaf(f[c], f[c], zn2acc);
      atomicAdd(&sumzd[dbase + c], f[c]);
      hv[c] = (short)f2bf(f[c]);
    }
    *(s16x4*)&sm.Zh[ds][slot * 8 + jh * 4] = *(s16x4*)hv;
  }
  atomicAdd(&zn2[nloc], zn2acc);
  __syncthreads();

  // ---- Phase B/C: two k-chunks, 16 MFMAs per 4 A-loads, fold between ----
  const bf16x8* __restrict__ E8 = (const bf16x8*)E2;
  const int kwb = w * 4;                 // ktg base within a 32-tile chunk

  float bestv[4];
  int   bestk[4];
  #pragma unroll
  for (int ni = 0; ni < 4; ++ni) { bestv[ni] = 3.0e38f; bestk[ni] = 0; }

  #pragma unroll
  for (int c = 0; c < 2; ++c) {
    f32x4 acc[4][4];
    #pragma unroll
    for (int kti = 0; kti < 4; ++kti)
      #pragma unroll
      for (int ni = 0; ni < 4; ++ni) acc[kti][ni] = (f32x4)0.0f;

    #pragma unroll
    for (int ds = 0; ds < 8; ++ds) {
      bf16x8 Av[4];
      #pragma unroll
      for (int kti = 0; kti < 4; ++kti)
        Av[kti] = E8[(size_t)((c * 32 + kwb + kti) * 8 + ds) * 64 + l];
      bf16x8 Bv[4];
      #pragma unroll
      for (int ni = 0; ni < 4; ++ni)
        Bv[ni] = *(const bf16x8*)&sm.Zh[ds][(ni * 64 + l) * 8];
      #pragma unroll
      for (int kti = 0; kti < 4; ++kti)
        #pragma unroll
        for (int ni = 0; ni < 4; ++ni)
          acc[kti][ni] = __builtin_amdgcn_mfma_f32_16x16x32_bf16(Av[kti], Bv[ni],
                                                                acc[kti][ni], 0, 0, 0);
    }
    // fold chunk c (k ascending per thread => first-min tiebreak)
    #pragma unroll
    for (int kti = 0; kti < 4; ++kti) {
      #pragma unroll
      for (int ni = 0; ni < 4; ++ni) {
        const f32x4 a = acc[kti][ni];
        #pragma unroll
        for (int r = 0; r < 4; ++r) {
          const int k = c * 512 + w * 64 + kti * 16 + quad * 4 + r;
          const float v = fmaf(-2.0f, a[r], en[k]);
          if (v < bestv[ni]) { bestv[ni] = v; bestk[ni] = k; }
        }
      }
    }
  }

  #pragma unroll
  for (int ni = 0; ni < 4; ++ni) {
    unsigned long long p = pack64(bestv[ni], bestk[ni]);
    unsigned long long p2 = __shfl_down(p, 32, 64); if (p2 < p) p = p2;
    p2 = __shfl_down(p, 16, 64);                    if (p2 < p) p = p2;
    if (quad == 0) red[w][ni * 16 + (l & 15)] = p;
  }
  __syncthreads();   // red ready; all Zh reads done

  if (t < 256) atomicAdd(&sum_z_d[t], sumzd[t]);
  if (t < 64) {
    unsigned long long m = red[0][t];
    #pragma unroll
    for (int i = 1; i < 8; ++i) { const unsigned long long c = red[i][t]; if (c < m) m = c; }
    const unsigned int k = (unsigned int)(m & 0xFFFFFFFFull);
    kbuf[t] = k;
    atomicAdd(&counts[k], 1u);
    const float dminv = unpack32((unsigned int)(m >> 32));
    const float z2    = zn2[t];
    float dsum = z2 + dminv;     // ||z_n - e_k||^2 (analytic)
    float zsum = z2;
    #pragma unroll
    for (int off = 32; off > 0; off >>= 1) {
      dsum += __shfl_down(dsum, off, 64);
      zsum += __shfl_down(zsum, off, 64);
    }
    if (t == 0) {
      atomicAdd(&scald[2], (double)dsum);
      atomicAdd(&scald[1], (double)zsum);
    }
  }
  __syncthreads();   // kbuf ready; Zh dead -> erow may overwrite

  // ---- Phase D: two 32-n passes: stage chosen e-rows, write out coalesced ----
  #pragma unroll
  for (int p = 0; p < 2; ++p) {
    {
      const int r  = t >> 4;            // 0..31 (n within pass)
      const int d0 = (t & 15) * 16;
      const unsigned int k = kbuf[p * 32 + r];
      const float* er = e + (size_t)k * D_ + d0;
      #pragma unroll
      for (int i = 0; i < 4; ++i) {
        const float4 f = *(const float4*)(er + i * 4);
        float* dst = &sm.erow[r * 257 + d0 + i * 4];
        dst[0] = f.x; dst[1] = f.y; dst[2] = f.z; dst[3] = f.w;
      }
    }
    __syncthreads();
    {
      const int s  = t >> 5;            // 0..15 -> d-slice of 16
      const int cc = t & 31;            // hw within pass
      float* ob = out + ((size_t)b * D_ + s * 16) * HW_ + hw0 + p * 32 + cc;
      #pragma unroll
      for (int i = 0; i < 16; ++i)
        ob[(size_t)i * HW_] = sm.erow[cc * 257 + s * 16 + i];
    }
    if (p == 0) __syncthreads();
  }
}

// ---------------------------------------------------------------------------
// finalize: loss, perplexity, mean_distance
// ---------------------------------------------------------------------------
__global__ void vq_final(const unsigned int* __restrict__ counts,
                         const float* __restrict__ enorm,
                         const float* __restrict__ sum_e_d, const float* __restrict__ sum_z_d,
                         const double* __restrict__ scald, float* __restrict__ out) {
  __shared__ float sred[4];
  const int t = threadIdx.x;
  float h = 0.0f;
  for (int i = t; i < K_; i += 256) {
    const float em = (float)counts[i] * (1.0f / (float)N_);
    h += em * logf(em + 1e-10f);
  }
  const float hs = blockReduceSum(h, sred);
  __syncthreads();
  const float dv = sum_z_d[t] * sum_e_d[t];
  const float dot = blockReduceSum(dv, sred);
  __syncthreads();
  float e2 = 0.0f;
  #pragma unroll
  for (int i = 0; i < 4; ++i) e2 += enorm[t + 256 * i];
  const float sume2 = blockReduceSum(e2, sred);
  if (t == 0) {
    const double loss = (double)(1.0f + BETA_) * scald[2] / (double)((size_t)N_ * D_);
    const float perp = expf(-hs);
    const double md = scald[1] / (double)N_ + (double)sume2 / (double)K_
                    - 2.0 * (double)dot / ((double)N_ * (double)K_);
    out[OUT0 + 0] = (float)loss;
    out[OUT0 + 1] = perp;
    out[OUT0 + 2] = (float)md;
  }
}

extern "C" void kernel_launch(void* const* d_in, const int* in_sizes, int n_in,
                              void* d_out, int out_size, void* d_ws, size_t ws_size,
                              hipStream_t stream) {
  const float* z = (const float*)d_in[0];        // [32,256,32,32]
  const float* e = (const float*)d_in[1];        // [1024,256]
  float* out = (float*)d_out;

  char* ws = (char*)d_ws;
  unsigned short* E2 = (unsigned short*)(ws + E2_OFF);
  float* enorm   = (float*)(ws + ENORM_OFF);
  float* sum_e_d = (float*)(ws + SUMED_OFF);
  float* sum_z_d = (float*)(ws + SUMZD_OFF);
  unsigned int* counts = (unsigned int*)(ws + CNT_OFF);
  double* scald  = (double*)(ws + SCAL_OFF);

  hipMemsetAsync(ws + ZERO_OFF, 0x00, (size_t)ZERO_BYTES, stream);

  vq_eprep  <<<dim3(64),  dim3(512), 0, stream>>>(e, E2, enorm, sum_e_d);
  vq_argmin4<<<dim3(512), dim3(512), 0, stream>>>(z, e, E2, enorm, out, counts,
                                                  sum_z_d, scald);
  vq_final  <<<dim3(1),   dim3(256), 0, stream>>>(counts, enorm, sum_e_d, sum_z_d,
                                                  scald, out);
}

// Round 5
// 214.071 us; speedup vs baseline: 1.6409x; 1.6409x over previous
//
#include <hip/hip_runtime.h>
#include <stdint.h>

#define B_    32
#define D_    256
#define HW_   1024
#define N_    32768      // B_*HW_
#define K_    1024
#define BETA_ 0.25f
#define OUT0  8388608    // N_*D_

typedef short bf16x8 __attribute__((ext_vector_type(8)));
typedef short s16x4  __attribute__((ext_vector_type(4)));
typedef float f32x4  __attribute__((ext_vector_type(4)));

// ---- workspace layout (bytes) ----
#define E2_OFF    0          // 512 KB  bf16 of E, A-fragment order (k-major)
#define ENORM_OFF 524288     // 4 KB    ||e_k||^2 fp32 (exact, from fp32 e)
#define SUMED_OFF 528384     // 1 KB    col sums of E
#define SUMZD_OFF 529408     // 1 KB    per-d sums of Z
#define CNT_OFF   530432     // 4 KB    histogram
#define SCAL_OFF  534528     // 32 B    doubles: [1]=sum z^2, [2]=sum diff^2
#define ZERO_OFF  SUMED_OFF
#define ZERO_BYTES (534560 - SUMED_OFF)

__device__ __forceinline__ unsigned short f2bf(float f) {
  unsigned int u = __float_as_uint(f);
  u += 0x7FFFu + ((u >> 16) & 1u);          // round-to-nearest-even
  return (unsigned short)(u >> 16);
}

__device__ __forceinline__ unsigned long long pack64(float v, int k) {
  unsigned int b = __float_as_uint(v);
  b = (b & 0x80000000u) ? ~b : (b | 0x80000000u);   // order-preserving map
  return ((unsigned long long)b << 32) | (unsigned int)k;
}

__device__ __forceinline__ float unpack32(unsigned int p) {
  p = (p & 0x80000000u) ? (p ^ 0x80000000u) : ~p;
  return __uint_as_float(p);
}

__device__ __forceinline__ float blockReduceSum(float v, volatile float* sred) {
  #pragma unroll
  for (int off = 32; off > 0; off >>= 1) v += __shfl_down(v, off, 64);
  __syncthreads();
  if ((threadIdx.x & 63) == 0) sred[threadIdx.x >> 6] = v;
  __syncthreads();
  float r = 0.0f;
  if (threadIdx.x == 0) {
    const int nw = blockDim.x >> 6;
    for (int i = 0; i < nw; ++i) r += sred[i];
  }
  return r;  // valid on thread 0 only
}

// ---------------------------------------------------------------------------
// E prep: single-bf16 A-fragment-ordered E, enorm[k] (exact fp32), col sums.
// Fragment index: fi = (ktg*8 + ds)*64 + lane,  ktg = k/16, ds = d/32.
// lane -> (m=lane&15 = k%16, d = ds*32 + (lane>>4)*8 + j).
// ---------------------------------------------------------------------------
__global__ void vq_eprep(const float* __restrict__ e, unsigned short* __restrict__ E2,
                         float* __restrict__ enorm, float* __restrict__ sum_e_d) {
  __shared__ float ered[16][33];
  __shared__ float sumed[256];
  const int t  = threadIdx.x;
  const int kt = blockIdx.x;
  const int ds = t >> 6, l = t & 63;
  const int q  = l >> 4, m = l & 15;
  const int k  = kt * 16 + m;
  const int d0 = ds * 32 + q * 8;
  if (t < 256) sumed[t] = 0.0f;
  __syncthreads();

  const float* ep = e + (size_t)k * D_ + d0;
  const float4 v0 = *(const float4*)ep;
  const float4 v1 = *(const float4*)(ep + 4);
  const float vv[8] = {v0.x, v0.y, v0.z, v0.w, v1.x, v1.y, v1.z, v1.w};
  short hv[8];
  float p = 0.0f;
  #pragma unroll
  for (int j = 0; j < 8; ++j) {
    const float f = vv[j];
    p += f * f;
    hv[j] = (short)f2bf(f);
    atomicAdd(&sumed[d0 + j], f);
  }
  const size_t fi = ((size_t)(kt * 8 + ds)) * 64 + l;
  *(bf16x8*)(E2 + fi * 8) = *(bf16x8*)hv;

  ered[m][ds * 4 + q] = p;
  __syncthreads();
  if (t < 16) {
    float s = 0.0f;
    #pragma unroll
    for (int i = 0; i < 32; ++i) s += ered[t][i];
    enorm[kt * 16 + t] = s;
  }
  if (t < 256) atomicAdd(&sum_e_d[t], sumed[t]);
}

// ---------------------------------------------------------------------------
// Fused argmin + gather, single-term bf16, spill-safe register budget.
// grid 512 (b x 16 hw-tiles of 64 n) x 512 thr, __launch_bounds__(512,4):
// 2 blocks/CU, 4 waves/SIMD.  Per pass: wave covers 32 k x 64 n
// (acc[2][4] = 32 AGPR); 4 passes walk the wave's 128-k range in ascending
// k order (first-min tiebreak preserved).  Pass loop is NOT unrolled to
// keep VGPR live-ranges bounded (R4 spill lesson).
// ---------------------------------------------------------------------------
__global__ __launch_bounds__(512, 4)
void vq_argmin5(const float* __restrict__ z, const float* __restrict__ e,
                const unsigned short* __restrict__ E2,
                const float* __restrict__ enorm_g,
                float* __restrict__ out, unsigned int* __restrict__ counts,
                float* __restrict__ sum_z_d, double* __restrict__ scald) {
  union SM {
    unsigned short Zh[8][2048];     // 32768 B: [ds][slot*8+j]
    float erow[32 * 257];           // 32896 B (epilogue staging, 32 n / pass)
  };
  __shared__ SM sm;
  __shared__ float en[1024];
  __shared__ unsigned long long red[8][64];
  __shared__ float sumzd[256];
  __shared__ float zn2[64];
  __shared__ unsigned int kbuf[64];

  const int t  = threadIdx.x;
  const int nt = blockIdx.x;
  const int b   = nt >> 4;
  const int hw0 = (nt & 15) << 6;
  const int w = t >> 6, l = t & 63;
  const int quad = l >> 4;

  // staging identity
  const int slot  = t & 255;
  const int jh    = t >> 8;                            // 0/1 -> j = jh*4 + c
  const int squad = (slot >> 4) & 3;
  const int nloc  = ((slot >> 6) << 4) + (slot & 15);  // ni*16 + n15
  const float* zb = z + (size_t)b * D_ * HW_ + hw0 + nloc;

  if (t < 256) sumzd[t] = 0.0f;
  if (t < 64)  zn2[t] = 0.0f;
  en[t] = enorm_g[t];
  en[t + 512] = enorm_g[t + 512];
  __syncthreads();

  // ---- Phase A: stage all of Z (single bf16) + exact fp32 stats ----
  float zn2acc = 0.0f;
  #pragma unroll 1
  for (int ds = 0; ds < 8; ++ds) {
    const int dbase = ds * 32 + squad * 8 + jh * 4;
    float f[4];
    #pragma unroll
    for (int c = 0; c < 4; ++c) f[c] = zb[(size_t)(dbase + c) * HW_];
    short hv[4];
    #pragma unroll
    for (int c = 0; c < 4; ++c) {
      zn2acc = fmaf(f[c], f[c], zn2acc);
      atomicAdd(&sumzd[dbase + c], f[c]);
      hv[c] = (short)f2bf(f[c]);
    }
    *(s16x4*)&sm.Zh[ds][slot * 8 + jh * 4] = *(s16x4*)hv;
  }
  atomicAdd(&zn2[nloc], zn2acc);
  __syncthreads();

  // ---- Phase B/C: 4 passes of 32k x 64n, fold argmin between passes ----
  const bf16x8* __restrict__ E8 = (const bf16x8*)E2;

  float bestv[4];
  int   bestk[4];
  #pragma unroll
  for (int ni = 0; ni < 4; ++ni) { bestv[ni] = 3.0e38f; bestk[ni] = 0; }

  #pragma unroll 1
  for (int p = 0; p < 4; ++p) {
    // ktg ascending in p for each thread => first-min tiebreak holds
    const int ktg0 = ((p >> 1) << 5) + (w << 2) + ((p & 1) << 1);

    f32x4 acc[2][4];
    #pragma unroll
    for (int kti = 0; kti < 2; ++kti)
      #pragma unroll
      for (int ni = 0; ni < 4; ++ni) acc[kti][ni] = (f32x4)0.0f;

    #pragma unroll
    for (int ds = 0; ds < 8; ++ds) {
      bf16x8 Av[2];
      Av[0] = E8[(size_t)((ktg0 * 8) + ds) * 64 + l];
      Av[1] = E8[(size_t)((ktg0 * 8) + 8 + ds) * 64 + l];
      bf16x8 Bv[4];
      #pragma unroll
      for (int ni = 0; ni < 4; ++ni)
        Bv[ni] = *(const bf16x8*)&sm.Zh[ds][(ni * 64 + l) * 8];
      #pragma unroll
      for (int kti = 0; kti < 2; ++kti)
        #pragma unroll
        for (int ni = 0; ni < 4; ++ni)
          acc[kti][ni] = __builtin_amdgcn_mfma_f32_16x16x32_bf16(Av[kti], Bv[ni],
                                                                acc[kti][ni], 0, 0, 0);
    }
    // fold this pass (k ascending within pass as well)
    #pragma unroll
    for (int kti = 0; kti < 2; ++kti) {
      const int kb = (ktg0 + kti) * 16 + quad * 4;
      const f32x4 en4 = *(const f32x4*)&en[kb];
      #pragma unroll
      for (int ni = 0; ni < 4; ++ni) {
        const f32x4 a = acc[kti][ni];
        #pragma unroll
        for (int r = 0; r < 4; ++r) {
          const float v = fmaf(-2.0f, a[r], en4[r]);
          if (v < bestv[ni]) { bestv[ni] = v; bestk[ni] = kb + r; }
        }
      }
    }
  }

  #pragma unroll
  for (int ni = 0; ni < 4; ++ni) {
    unsigned long long p = pack64(bestv[ni], bestk[ni]);
    unsigned long long p2 = __shfl_down(p, 32, 64); if (p2 < p) p = p2;
    p2 = __shfl_down(p, 16, 64);                    if (p2 < p) p = p2;
    if (quad == 0) red[w][ni * 16 + (l & 15)] = p;
  }
  __syncthreads();   // red ready; all Zh reads done

  if (t < 256) atomicAdd(&sum_z_d[t], sumzd[t]);
  if (t < 64) {
    unsigned long long m = red[0][t];
    #pragma unroll
    for (int i = 1; i < 8; ++i) { const unsigned long long c = red[i][t]; if (c < m) m = c; }
    const unsigned int k = (unsigned int)(m & 0xFFFFFFFFull);
    kbuf[t] = k;
    atomicAdd(&counts[k], 1u);
    const float dminv = unpack32((unsigned int)(m >> 32));
    const float z2    = zn2[t];
    float dsum = z2 + dminv;     // ||z_n - e_k||^2 (analytic)
    float zsum = z2;
    #pragma unroll
    for (int off = 32; off > 0; off >>= 1) {
      dsum += __shfl_down(dsum, off, 64);
      zsum += __shfl_down(zsum, off, 64);
    }
    if (t == 0) {
      atomicAdd(&scald[2], (double)dsum);
      atomicAdd(&scald[1], (double)zsum);
    }
  }
  __syncthreads();   // kbuf ready; Zh dead -> erow may overwrite

  // ---- Phase D: two 32-n passes: stage chosen e-rows, write out coalesced ----
  #pragma unroll 1
  for (int p = 0; p < 2; ++p) {
    {
      const int r  = t >> 4;            // 0..31 (n within pass)
      const int d0 = (t & 15) * 16;
      const unsigned int k = kbuf[p * 32 + r];
      const float* er = e + (size_t)k * D_ + d0;
      #pragma unroll
      for (int i = 0; i < 4; ++i) {
        const float4 f = *(const float4*)(er + i * 4);
        float* dst = &sm.erow[r * 257 + d0 + i * 4];
        dst[0] = f.x; dst[1] = f.y; dst[2] = f.z; dst[3] = f.w;
      }
    }
    __syncthreads();
    {
      const int s  = t >> 5;            // 0..15 -> d-slice of 16
      const int cc = t & 31;            // hw within pass
      float* ob = out + ((size_t)b * D_ + s * 16) * HW_ + hw0 + p * 32 + cc;
      #pragma unroll
      for (int i = 0; i < 16; ++i)
        ob[(size_t)i * HW_] = sm.erow[cc * 257 + s * 16 + i];
    }
    if (p == 0) __syncthreads();
  }
}

// ---------------------------------------------------------------------------
// finalize: loss, perplexity, mean_distance
// ---------------------------------------------------------------------------
__global__ void vq_final(const unsigned int* __restrict__ counts,
                         const float* __restrict__ enorm,
                         const float* __restrict__ sum_e_d, const float* __restrict__ sum_z_d,
                         const double* __restrict__ scald, float* __restrict__ out) {
  __shared__ float sred[4];
  const int t = threadIdx.x;
  float h = 0.0f;
  for (int i = t; i < K_; i += 256) {
    const float em = (float)counts[i] * (1.0f / (float)N_);
    h += em * logf(em + 1e-10f);
  }
  const float hs = blockReduceSum(h, sred);
  __syncthreads();
  const float dv = sum_z_d[t] * sum_e_d[t];
  const float dot = blockReduceSum(dv, sred);
  __syncthreads();
  float e2 = 0.0f;
  #pragma unroll
  for (int i = 0; i < 4; ++i) e2 += enorm[t + 256 * i];
  const float sume2 = blockReduceSum(e2, sred);
  if (t == 0) {
    const double loss = (double)(1.0f + BETA_) * scald[2] / (double)((size_t)N_ * D_);
    const float perp = expf(-hs);
    const double md = scald[1] / (double)N_ + (double)sume2 / (double)K_
                    - 2.0 * (double)dot / ((double)N_ * (double)K_);
    out[OUT0 + 0] = (float)loss;
    out[OUT0 + 1] = perp;
    out[OUT0 + 2] = (float)md;
  }
}

extern "C" void kernel_launch(void* const* d_in, const int* in_sizes, int n_in,
                              void* d_out, int out_size, void* d_ws, size_t ws_size,
                              hipStream_t stream) {
  const float* z = (const float*)d_in[0];        // [32,256,32,32]
  const float* e = (const float*)d_in[1];        // [1024,256]
  float* out = (float*)d_out;

  char* ws = (char*)d_ws;
  unsigned short* E2 = (unsigned short*)(ws + E2_OFF);
  float* enorm   = (float*)(ws + ENORM_OFF);
  float* sum_e_d = (float*)(ws + SUMED_OFF);
  float* sum_z_d = (float*)(ws + SUMZD_OFF);
  unsigned int* counts = (unsigned int*)(ws + CNT_OFF);
  double* scald  = (double*)(ws + SCAL_OFF);

  hipMemsetAsync(ws + ZERO_OFF, 0x00, (size_t)ZERO_BYTES, stream);

  vq_eprep   <<<dim3(64),  dim3(512), 0, stream>>>(e, E2, enorm, sum_e_d);
  vq_argmin5 <<<dim3(512), dim3(512), 0, stream>>>(z, e, E2, enorm, out, counts,
                                                   sum_z_d, scald);
  vq_final   <<<dim3(1),   dim3(256), 0, stream>>>(counts, enorm, sum_e_d, sum_z_d,
                                                   scald, out);
}

// Round 6
// 193.284 us; speedup vs baseline: 1.8173x; 1.1075x over previous
//
#include <hip/hip_runtime.h>
#include <stdint.h>

#define B_    32
#define D_    256
#define HW_   1024
#define N_    32768      // B_*HW_
#define K_    1024
#define BETA_ 0.25f
#define OUT0  8388608    // N_*D_

typedef short bf16x8 __attribute__((ext_vector_type(8)));
typedef short s16x4  __attribute__((ext_vector_type(4)));
typedef float f32x4  __attribute__((ext_vector_type(4)));

// ---- workspace layout (bytes) ----
#define E2_OFF    0          // 512 KB  bf16 of E, A-fragment order (k-major)
#define ENORM_OFF 524288     // 4 KB    ||e_k||^2 fp32 (exact, from fp32 e)
#define SUMED_OFF 528384     // 1 KB    col sums of E
#define SUMZD_OFF 529408     // 1 KB    per-d sums of Z
#define CNT_OFF   530432     // 4 KB    histogram
#define SCAL_OFF  534528     // 32 B    doubles: [1]=sum z^2, [2]=sum diff^2
#define ZERO_OFF  SUMED_OFF
#define ZERO_BYTES (534560 - SUMED_OFF)

__device__ __forceinline__ unsigned short f2bf(float f) {
  unsigned int u = __float_as_uint(f);
  u += 0x7FFFu + ((u >> 16) & 1u);          // round-to-nearest-even
  return (unsigned short)(u >> 16);
}

__device__ __forceinline__ unsigned long long pack64(float v, int k) {
  unsigned int b = __float_as_uint(v);
  b = (b & 0x80000000u) ? ~b : (b | 0x80000000u);   // order-preserving map
  return ((unsigned long long)b << 32) | (unsigned int)k;
}

__device__ __forceinline__ float unpack32(unsigned int p) {
  p = (p & 0x80000000u) ? (p ^ 0x80000000u) : ~p;
  return __uint_as_float(p);
}

__device__ __forceinline__ float blockReduceSum(float v, volatile float* sred) {
  #pragma unroll
  for (int off = 32; off > 0; off >>= 1) v += __shfl_down(v, off, 64);
  __syncthreads();
  if ((threadIdx.x & 63) == 0) sred[threadIdx.x >> 6] = v;
  __syncthreads();
  float r = 0.0f;
  if (threadIdx.x == 0) {
    const int nw = blockDim.x >> 6;
    for (int i = 0; i < nw; ++i) r += sred[i];
  }
  return r;  // valid on thread 0 only
}

// ---------------------------------------------------------------------------
// E prep: single-bf16 A-fragment-ordered E, enorm[k] (exact fp32), col sums.
// Fragment index: fi = (ktg*8 + ds)*64 + lane,  ktg = k/16, ds = d/32.
// lane -> (m=lane&15 = k%16, d = ds*32 + (lane>>4)*8 + j).
// ---------------------------------------------------------------------------
__global__ void vq_eprep(const float* __restrict__ e, unsigned short* __restrict__ E2,
                         float* __restrict__ enorm, float* __restrict__ sum_e_d) {
  __shared__ float ered[16][33];
  __shared__ float sumed[256];
  const int t  = threadIdx.x;
  const int kt = blockIdx.x;
  const int ds = t >> 6, l = t & 63;
  const int q  = l >> 4, m = l & 15;
  const int k  = kt * 16 + m;
  const int d0 = ds * 32 + q * 8;
  if (t < 256) sumed[t] = 0.0f;
  __syncthreads();

  const float* ep = e + (size_t)k * D_ + d0;
  const float4 v0 = *(const float4*)ep;
  const float4 v1 = *(const float4*)(ep + 4);
  const float vv[8] = {v0.x, v0.y, v0.z, v0.w, v1.x, v1.y, v1.z, v1.w};
  short hv[8];
  float p = 0.0f;
  #pragma unroll
  for (int j = 0; j < 8; ++j) {
    const float f = vv[j];
    p += f * f;
    hv[j] = (short)f2bf(f);
    atomicAdd(&sumed[d0 + j], f);
  }
  const size_t fi = ((size_t)(kt * 8 + ds)) * 64 + l;
  *(bf16x8*)(E2 + fi * 8) = *(bf16x8*)hv;

  ered[m][ds * 4 + q] = p;
  __syncthreads();
  if (t < 16) {
    float s = 0.0f;
    #pragma unroll
    for (int i = 0; i < 32; ++i) s += ered[t][i];
    enorm[kt * 16 + t] = s;
  }
  if (t < 256) atomicAdd(&sum_e_d[t], sumed[t]);
}

// ---------------------------------------------------------------------------
// Fused argmin + gather, single-term bf16.
// grid 512 (b x 16 hw-tiles of 64 n) x 512 thr, __launch_bounds__(512,4):
// target 2 blocks/CU, 4 waves/SIMD. acc[2][4] = 32 AGPR; arch-VGPR budget
// is clamped to 64 by the allocator when AGPRs are present (R4/R5 evidence),
// so the ds-loop is unrolled only 2x to keep <=4 global A-loads + 8 B-frags
// live (~55 arch VGPRs) and avoid the scratch spills that dominated R4/R5.
// ---------------------------------------------------------------------------
__global__ __launch_bounds__(512, 4)
void vq_argmin6(const float* __restrict__ z, const float* __restrict__ e,
                const unsigned short* __restrict__ E2,
                const float* __restrict__ enorm_g,
                float* __restrict__ out, unsigned int* __restrict__ counts,
                float* __restrict__ sum_z_d, double* __restrict__ scald) {
  union SM {
    unsigned short Zh[8][2048];     // 32768 B: [ds][slot*8+j]
    float erow[32 * 257];           // 32896 B (epilogue staging, 32 n / pass)
  };
  __shared__ SM sm;
  __shared__ float en[1024];
  __shared__ unsigned long long red[8][64];
  __shared__ float sumzd[256];
  __shared__ float zn2[64];
  __shared__ unsigned int kbuf[64];

  const int t  = threadIdx.x;
  const int nt = blockIdx.x;
  const int b   = nt >> 4;
  const int hw0 = (nt & 15) << 6;
  const int w = t >> 6, l = t & 63;
  const int quad = l >> 4;

  // staging identity
  const int slot  = t & 255;
  const int jh    = t >> 8;                            // 0/1 -> j = jh*4 + c
  const int squad = (slot >> 4) & 3;
  const int nloc  = ((slot >> 6) << 4) + (slot & 15);  // ni*16 + n15
  const float* zb = z + (size_t)b * D_ * HW_ + hw0 + nloc;

  if (t < 256) sumzd[t] = 0.0f;
  if (t < 64)  zn2[t] = 0.0f;
  en[t] = enorm_g[t];
  en[t + 512] = enorm_g[t + 512];
  __syncthreads();

  // ---- Phase A: stage all of Z (single bf16) + exact fp32 stats ----
  float zn2acc = 0.0f;
  #pragma unroll 1
  for (int ds = 0; ds < 8; ++ds) {
    const int dbase = ds * 32 + squad * 8 + jh * 4;
    float f[4];
    #pragma unroll
    for (int c = 0; c < 4; ++c) f[c] = zb[(size_t)(dbase + c) * HW_];
    short hv[4];
    #pragma unroll
    for (int c = 0; c < 4; ++c) {
      zn2acc = fmaf(f[c], f[c], zn2acc);
      atomicAdd(&sumzd[dbase + c], f[c]);
      hv[c] = (short)f2bf(f[c]);
    }
    *(s16x4*)&sm.Zh[ds][slot * 8 + jh * 4] = *(s16x4*)hv;
  }
  atomicAdd(&zn2[nloc], zn2acc);
  __syncthreads();

  // ---- Phase B/C: 4 passes of 32k x 64n, fold argmin between passes ----
  const bf16x8* __restrict__ E8 = (const bf16x8*)E2;

  float bestv[4];
  int   bestk[4];
  #pragma unroll
  for (int ni = 0; ni < 4; ++ni) { bestv[ni] = 3.0e38f; bestk[ni] = 0; }

  #pragma unroll 1
  for (int p = 0; p < 4; ++p) {
    // ktg ascending in p for each thread => first-min tiebreak holds
    const int ktg0 = ((p >> 1) << 5) + (w << 2) + ((p & 1) << 1);

    f32x4 acc[2][4];
    #pragma unroll
    for (int kti = 0; kti < 2; ++kti)
      #pragma unroll
      for (int ni = 0; ni < 4; ++ni) acc[kti][ni] = (f32x4)0.0f;

    #pragma unroll 2
    for (int ds = 0; ds < 8; ++ds) {
      bf16x8 Av[2];
      Av[0] = E8[(size_t)((ktg0 * 8) + ds) * 64 + l];
      Av[1] = E8[(size_t)((ktg0 * 8) + 8 + ds) * 64 + l];
      bf16x8 Bv[4];
      #pragma unroll
      for (int ni = 0; ni < 4; ++ni)
        Bv[ni] = *(const bf16x8*)&sm.Zh[ds][(ni * 64 + l) * 8];
      #pragma unroll
      for (int kti = 0; kti < 2; ++kti)
        #pragma unroll
        for (int ni = 0; ni < 4; ++ni)
          acc[kti][ni] = __builtin_amdgcn_mfma_f32_16x16x32_bf16(Av[kti], Bv[ni],
                                                                acc[kti][ni], 0, 0, 0);
    }
    // fold this pass (k ascending within pass as well)
    #pragma unroll
    for (int kti = 0; kti < 2; ++kti) {
      const int kb = (ktg0 + kti) * 16 + quad * 4;
      const f32x4 en4 = *(const f32x4*)&en[kb];
      #pragma unroll
      for (int ni = 0; ni < 4; ++ni) {
        const f32x4 a = acc[kti][ni];
        #pragma unroll
        for (int r = 0; r < 4; ++r) {
          const float v = fmaf(-2.0f, a[r], en4[r]);
          if (v < bestv[ni]) { bestv[ni] = v; bestk[ni] = kb + r; }
        }
      }
    }
  }

  #pragma unroll
  for (int ni = 0; ni < 4; ++ni) {
    unsigned long long p = pack64(bestv[ni], bestk[ni]);
    unsigned long long p2 = __shfl_down(p, 32, 64); if (p2 < p) p = p2;
    p2 = __shfl_down(p, 16, 64);                    if (p2 < p) p = p2;
    if (quad == 0) red[w][ni * 16 + (l & 15)] = p;
  }
  __syncthreads();   // red ready; all Zh reads done

  if (t < 256) atomicAdd(&sum_z_d[t], sumzd[t]);
  if (t < 64) {
    unsigned long long m = red[0][t];
    #pragma unroll
    for (int i = 1; i < 8; ++i) { const unsigned long long c = red[i][t]; if (c < m) m = c; }
    const unsigned int k = (unsigned int)(m & 0xFFFFFFFFull);
    kbuf[t] = k;
    atomicAdd(&counts[k], 1u);
    const float dminv = unpack32((unsigned int)(m >> 32));
    const float z2    = zn2[t];
    float dsum = z2 + dminv;     // ||z_n - e_k||^2 (analytic)
    float zsum = z2;
    #pragma unroll
    for (int off = 32; off > 0; off >>= 1) {
      dsum += __shfl_down(dsum, off, 64);
      zsum += __shfl_down(zsum, off, 64);
    }
    if (t == 0) {
      atomicAdd(&scald[2], (double)dsum);
      atomicAdd(&scald[1], (double)zsum);
    }
  }
  __syncthreads();   // kbuf ready; Zh dead -> erow may overwrite

  // ---- Phase D: two 32-n passes: stage chosen e-rows, write out coalesced ----
  #pragma unroll 1
  for (int p = 0; p < 2; ++p) {
    {
      const int r  = t >> 4;            // 0..31 (n within pass)
      const int d0 = (t & 15) * 16;
      const unsigned int k = kbuf[p * 32 + r];
      const float* er = e + (size_t)k * D_ + d0;
      #pragma unroll
      for (int i = 0; i < 4; ++i) {
        const float4 f = *(const float4*)(er + i * 4);
        float* dst = &sm.erow[r * 257 + d0 + i * 4];
        dst[0] = f.x; dst[1] = f.y; dst[2] = f.z; dst[3] = f.w;
      }
    }
    __syncthreads();
    {
      const int s  = t >> 5;            // 0..15 -> d-slice of 16
      const int cc = t & 31;            // hw within pass
      float* ob = out + ((size_t)b * D_ + s * 16) * HW_ + hw0 + p * 32 + cc;
      #pragma unroll
      for (int i = 0; i < 16; ++i)
        ob[(size_t)i * HW_] = sm.erow[cc * 257 + s * 16 + i];
    }
    if (p == 0) __syncthreads();
  }
}

// ---------------------------------------------------------------------------
// finalize: loss, perplexity, mean_distance
// ---------------------------------------------------------------------------
__global__ void vq_final(const unsigned int* __restrict__ counts,
                         const float* __restrict__ enorm,
                         const float* __restrict__ sum_e_d, const float* __restrict__ sum_z_d,
                         const double* __restrict__ scald, float* __restrict__ out) {
  __shared__ float sred[4];
  const int t = threadIdx.x;
  float h = 0.0f;
  for (int i = t; i < K_; i += 256) {
    const float em = (float)counts[i] * (1.0f / (float)N_);
    h += em * logf(em + 1e-10f);
  }
  const float hs = blockReduceSum(h, sred);
  __syncthreads();
  const float dv = sum_z_d[t] * sum_e_d[t];
  const float dot = blockReduceSum(dv, sred);
  __syncthreads();
  float e2 = 0.0f;
  #pragma unroll
  for (int i = 0; i < 4; ++i) e2 += enorm[t + 256 * i];
  const float sume2 = blockReduceSum(e2, sred);
  if (t == 0) {
    const double loss = (double)(1.0f + BETA_) * scald[2] / (double)((size_t)N_ * D_);
    const float perp = expf(-hs);
    const double md = scald[1] / (double)N_ + (double)sume2 / (double)K_
                    - 2.0 * (double)dot / ((double)N_ * (double)K_);
    out[OUT0 + 0] = (float)loss;
    out[OUT0 + 1] = perp;
    out[OUT0 + 2] = (float)md;
  }
}

extern "C" void kernel_launch(void* const* d_in, const int* in_sizes, int n_in,
                              void* d_out, int out_size, void* d_ws, size_t ws_size,
                              hipStream_t stream) {
  const float* z = (const float*)d_in[0];        // [32,256,32,32]
  const float* e = (const float*)d_in[1];        // [1024,256]
  float* out = (float*)d_out;

  char* ws = (char*)d_ws;
  unsigned short* E2 = (unsigned short*)(ws + E2_OFF);
  float* enorm   = (float*)(ws + ENORM_OFF);
  float* sum_e_d = (float*)(ws + SUMED_OFF);
  float* sum_z_d = (float*)(ws + SUMZD_OFF);
  unsigned int* counts = (unsigned int*)(ws + CNT_OFF);
  double* scald  = (double*)(ws + SCAL_OFF);

  hipMemsetAsync(ws + ZERO_OFF, 0x00, (size_t)ZERO_BYTES, stream);

  vq_eprep   <<<dim3(64),  dim3(512), 0, stream>>>(e, E2, enorm, sum_e_d);
  vq_argmin6 <<<dim3(512), dim3(512), 0, stream>>>(z, e, E2, enorm, out, counts,
                                                   sum_z_d, scald);
  vq_final   <<<dim3(1),   dim3(256), 0, stream>>>(counts, enorm, sum_e_d, sum_z_d,
                                                   scald, out);
}

// Round 7
// 137.311 us; speedup vs baseline: 2.5581x; 1.4076x over previous
//
#include <hip/hip_runtime.h>
#include <stdint.h>

#define B_    32
#define D_    256
#define HW_   1024
#define N_    32768      // B_*HW_
#define K_    1024
#define BETA_ 0.25f
#define OUT0  8388608    // N_*D_

typedef short bf16x8 __attribute__((ext_vector_type(8)));
typedef short s16x4  __attribute__((ext_vector_type(4)));
typedef float f32x4  __attribute__((ext_vector_type(4)));

// ---- workspace layout (bytes) ----
#define E2_OFF    0          // 512 KB  bf16 of E, A-fragment order (k-major)
#define ENORM_OFF 524288     // 4 KB    ||e_k||^2 fp32 (exact, from fp32 e)
#define SUMED_OFF 528384     // 1 KB    col sums of E
#define SUMZD_OFF 529408     // 1 KB    per-d sums of Z
#define CNT_OFF   530432     // 4 KB    histogram
#define SCAL_OFF  534528     // 32 B    doubles: [1]=sum z^2, [2]=sum diff^2
#define ZERO_OFF  SUMED_OFF
#define ZERO_BYTES (534560 - SUMED_OFF)

__device__ __forceinline__ unsigned short f2bf(float f) {
  unsigned int u = __float_as_uint(f);
  u += 0x7FFFu + ((u >> 16) & 1u);          // round-to-nearest-even
  return (unsigned short)(u >> 16);
}

__device__ __forceinline__ unsigned long long pack64(float v, int k) {
  unsigned int b = __float_as_uint(v);
  b = (b & 0x80000000u) ? ~b : (b | 0x80000000u);   // order-preserving map
  return ((unsigned long long)b << 32) | (unsigned int)k;
}

__device__ __forceinline__ float unpack32(unsigned int p) {
  p = (p & 0x80000000u) ? (p ^ 0x80000000u) : ~p;
  return __uint_as_float(p);
}

__device__ __forceinline__ float blockReduceSum(float v, volatile float* sred) {
  #pragma unroll
  for (int off = 32; off > 0; off >>= 1) v += __shfl_down(v, off, 64);
  __syncthreads();
  if ((threadIdx.x & 63) == 0) sred[threadIdx.x >> 6] = v;
  __syncthreads();
  float r = 0.0f;
  if (threadIdx.x == 0) {
    const int nw = blockDim.x >> 6;
    for (int i = 0; i < nw; ++i) r += sred[i];
  }
  return r;  // valid on thread 0 only
}

// ---------------------------------------------------------------------------
// E prep + Z stats.  grid 256 x 512.
// Blocks 0..63: also convert E to A-fragment-ordered bf16, enorm[k], col sums.
//   Fragment index: fi = (ktg*8 + ds)*64 + lane,  ktg = k/16, ds = d/32.
//   lane -> (m=lane&15 = k%16, d = ds*32 + (lane>>4)*8 + j).
// ALL blocks: reduce a 32-row slice of z -> sum_z_d[d] (global atomics, 1 per
//   row per block) and sum z^2 -> scald[1].  This removes the LDS-atomic
//   storm from the main kernel (R6 post-mortem: ~16-way same-address RMW
//   serialization dominated the DS pipe there).
// ---------------------------------------------------------------------------
__global__ __launch_bounds__(512)
void vq_eprep(const float* __restrict__ e, const float* __restrict__ z,
              unsigned short* __restrict__ E2, float* __restrict__ enorm,
              float* __restrict__ sum_e_d, float* __restrict__ sum_z_d,
              double* __restrict__ scald) {
  __shared__ float ered[16][33];
  __shared__ float sumed[256];
  __shared__ float sred[8];
  const int t   = threadIdx.x;
  const int blk = blockIdx.x;

  if (blk < 64) {                      // ---- E-part (block-uniform branch) ----
    const int kt = blk;
    const int ds = t >> 6, l = t & 63;
    const int q  = l >> 4, m = l & 15;
    const int k  = kt * 16 + m;
    const int d0 = ds * 32 + q * 8;
    if (t < 256) sumed[t] = 0.0f;
    __syncthreads();

    const float* ep = e + (size_t)k * D_ + d0;
    const float4 v0 = *(const float4*)ep;
    const float4 v1 = *(const float4*)(ep + 4);
    const float vv[8] = {v0.x, v0.y, v0.z, v0.w, v1.x, v1.y, v1.z, v1.w};
    short hv[8];
    float p = 0.0f;
    #pragma unroll
    for (int j = 0; j < 8; ++j) {
      const float f = vv[j];
      p += f * f;
      hv[j] = (short)f2bf(f);
      // quad-reduce: 16 lanes of a quad share d0 (different k) -> 1 atomic/16
      float s = f;
      #pragma unroll
      for (int off = 1; off < 16; off <<= 1) s += __shfl_xor(s, off, 16);
      if ((l & 15) == 0) atomicAdd(&sumed[d0 + j], s);
    }
    const size_t fi = ((size_t)(kt * 8 + ds)) * 64 + l;
    *(bf16x8*)(E2 + fi * 8) = *(bf16x8*)hv;

    ered[m][ds * 4 + q] = p;
    __syncthreads();
    if (t < 16) {
      float s = 0.0f;
      #pragma unroll
      for (int i = 0; i < 32; ++i) s += ered[t][i];
      enorm[kt * 16 + t] = s;
    }
    if (t < 256) atomicAdd(&sum_e_d[t], sumed[t]);
  }

  // ---- Z-stats part (all blocks): 32 (b,d)-rows of 1024 floats ----
  {
    const int b  = blk >> 3;
    const int dg = (blk & 7) << 5;
    const int r  = t >> 4;             // 0..31 row within slice
    const int c  = t & 15;             // 16 lanes share a row (one quad)
    const float* zr = z + ((size_t)(b * D_ + dg + r)) * HW_;
    float s = 0.0f, s2 = 0.0f;
    #pragma unroll 4
    for (int i = 0; i < 16; ++i) {
      const float4 f = *(const float4*)(zr + i * 64 + c * 4);
      s  += (f.x + f.y) + (f.z + f.w);
      s2 += f.x * f.x + f.y * f.y + f.z * f.z + f.w * f.w;
    }
    float ssum = s;
    #pragma unroll
    for (int off = 1; off < 16; off <<= 1) ssum += __shfl_xor(ssum, off, 16);
    if (c == 0) atomicAdd(&sum_z_d[dg + r], ssum);
    const float rs2 = blockReduceSum(s2, sred);
    if (t == 0) atomicAdd(&scald[1], (double)rs2);
  }
}

// ---------------------------------------------------------------------------
// Fused argmin + gather, single-term bf16.
// grid 512 (b x 16 hw-tiles of 64 n) x 512 thr, __launch_bounds__(512,4):
// 2 blocks/CU, 4 waves/SIMD.  acc[2][4] = 32 AGPR, ds-loop unrolled 2x
// (R4/R5 spill lesson: arch-VGPR clamped to 64 when AGPRs present).
// Phase A is now atomic-free except one 4-way zn2 atomic per thread
// (R6 lesson: the per-element sumzd atomics were a ~16-way-serialized
// DS-pipe storm that dominated the kernel).
// ---------------------------------------------------------------------------
__global__ __launch_bounds__(512, 4)
void vq_argmin7(const float* __restrict__ z, const float* __restrict__ e,
                const unsigned short* __restrict__ E2,
                const float* __restrict__ enorm_g,
                float* __restrict__ out, unsigned int* __restrict__ counts,
                double* __restrict__ scald) {
  union SM {
    unsigned short Zh[8][2048];     // 32768 B: [ds][slot*8+j]
    float erow[32 * 257];           // 32896 B (epilogue staging, 32 n / pass)
  };
  __shared__ SM sm;
  __shared__ float en[1024];
  __shared__ unsigned long long red[8][64];
  __shared__ float zn2[64];
  __shared__ unsigned int kbuf[64];

  const int t  = threadIdx.x;
  const int nt = blockIdx.x;
  const int b   = nt >> 4;
  const int hw0 = (nt & 15) << 6;
  const int w = t >> 6, l = t & 63;
  const int quad = l >> 4;

  // staging identity
  const int slot  = t & 255;
  const int jh    = t >> 8;                            // 0/1 -> j = jh*4 + c
  const int squad = (slot >> 4) & 3;
  const int nloc  = ((slot >> 6) << 4) + (slot & 15);  // ni*16 + n15
  const float* zb = z + (size_t)b * D_ * HW_ + hw0 + nloc;

  if (t < 64)  zn2[t] = 0.0f;
  en[t] = enorm_g[t];
  en[t + 512] = enorm_g[t + 512];
  __syncthreads();

  // ---- Phase A: stage all of Z (single bf16) + per-n ||z||^2 ----
  float zn2acc = 0.0f;
  #pragma unroll 1
  for (int ds = 0; ds < 8; ++ds) {
    const int dbase = ds * 32 + squad * 8 + jh * 4;
    float f[4];
    #pragma unroll
    for (int c = 0; c < 4; ++c) f[c] = zb[(size_t)(dbase + c) * HW_];
    short hv[4];
    #pragma unroll
    for (int c = 0; c < 4; ++c) {
      zn2acc = fmaf(f[c], f[c], zn2acc);
      hv[c] = (short)f2bf(f[c]);
    }
    *(s16x4*)&sm.Zh[ds][slot * 8 + jh * 4] = *(s16x4*)hv;
  }
  atomicAdd(&zn2[nloc], zn2acc);     // 4-way same-address only
  __syncthreads();

  // ---- Phase B/C: 4 passes of 32k x 64n, fold argmin between passes ----
  const bf16x8* __restrict__ E8 = (const bf16x8*)E2;

  float bestv[4];
  int   bestk[4];
  #pragma unroll
  for (int ni = 0; ni < 4; ++ni) { bestv[ni] = 3.0e38f; bestk[ni] = 0; }

  #pragma unroll 1
  for (int p = 0; p < 4; ++p) {
    // ktg ascending in p for each thread => first-min tiebreak holds
    const int ktg0 = ((p >> 1) << 5) + (w << 2) + ((p & 1) << 1);

    f32x4 acc[2][4];
    #pragma unroll
    for (int kti = 0; kti < 2; ++kti)
      #pragma unroll
      for (int ni = 0; ni < 4; ++ni) acc[kti][ni] = (f32x4)0.0f;

    #pragma unroll 2
    for (int ds = 0; ds < 8; ++ds) {
      bf16x8 Av[2];
      Av[0] = E8[(size_t)((ktg0 * 8) + ds) * 64 + l];
      Av[1] = E8[(size_t)((ktg0 * 8) + 8 + ds) * 64 + l];
      bf16x8 Bv[4];
      #pragma unroll
      for (int ni = 0; ni < 4; ++ni)
        Bv[ni] = *(const bf16x8*)&sm.Zh[ds][(ni * 64 + l) * 8];
      #pragma unroll
      for (int kti = 0; kti < 2; ++kti)
        #pragma unroll
        for (int ni = 0; ni < 4; ++ni)
          acc[kti][ni] = __builtin_amdgcn_mfma_f32_16x16x32_bf16(Av[kti], Bv[ni],
                                                                acc[kti][ni], 0, 0, 0);
    }
    // fold this pass (k ascending within pass as well)
    #pragma unroll
    for (int kti = 0; kti < 2; ++kti) {
      const int kb = (ktg0 + kti) * 16 + quad * 4;
      const f32x4 en4 = *(const f32x4*)&en[kb];
      #pragma unroll
      for (int ni = 0; ni < 4; ++ni) {
        const f32x4 a = acc[kti][ni];
        #pragma unroll
        for (int r = 0; r < 4; ++r) {
          const float v = fmaf(-2.0f, a[r], en4[r]);
          if (v < bestv[ni]) { bestv[ni] = v; bestk[ni] = kb + r; }
        }
      }
    }
  }

  #pragma unroll
  for (int ni = 0; ni < 4; ++ni) {
    unsigned long long p = pack64(bestv[ni], bestk[ni]);
    unsigned long long p2 = __shfl_down(p, 32, 64); if (p2 < p) p = p2;
    p2 = __shfl_down(p, 16, 64);                    if (p2 < p) p = p2;
    if (quad == 0) red[w][ni * 16 + (l & 15)] = p;
  }
  __syncthreads();   // red + zn2 ready; all Zh reads done

  if (t < 64) {
    unsigned long long m = red[0][t];
    #pragma unroll
    for (int i = 1; i < 8; ++i) { const unsigned long long c = red[i][t]; if (c < m) m = c; }
    const unsigned int k = (unsigned int)(m & 0xFFFFFFFFull);
    kbuf[t] = k;
    atomicAdd(&counts[k], 1u);
    const float dminv = unpack32((unsigned int)(m >> 32));
    float dsum = zn2[t] + dminv;     // ||z_n - e_k||^2 (analytic)
    #pragma unroll
    for (int off = 32; off > 0; off >>= 1) dsum += __shfl_down(dsum, off, 64);
    if (t == 0) atomicAdd(&scald[2], (double)dsum);
  }
  __syncthreads();   // kbuf ready; Zh dead -> erow may overwrite

  // ---- Phase D: two 32-n passes: stage chosen e-rows, write out coalesced ----
  #pragma unroll 1
  for (int p = 0; p < 2; ++p) {
    {
      const int r  = t >> 4;            // 0..31 (n within pass)
      const int d0 = (t & 15) * 16;
      const unsigned int k = kbuf[p * 32 + r];
      const float* er = e + (size_t)k * D_ + d0;
      #pragma unroll
      for (int i = 0; i < 4; ++i) {
        const float4 f = *(const float4*)(er + i * 4);
        float* dst = &sm.erow[r * 257 + d0 + i * 4];
        dst[0] = f.x; dst[1] = f.y; dst[2] = f.z; dst[3] = f.w;
      }
    }
    __syncthreads();
    {
      const int s  = t >> 5;            // 0..15 -> d-slice of 16
      const int cc = t & 31;            // hw within pass
      float* ob = out + ((size_t)b * D_ + s * 16) * HW_ + hw0 + p * 32 + cc;
      #pragma unroll
      for (int i = 0; i < 16; ++i)
        ob[(size_t)i * HW_] = sm.erow[cc * 257 + s * 16 + i];
    }
    if (p == 0) __syncthreads();
  }
}

// ---------------------------------------------------------------------------
// finalize: loss, perplexity, mean_distance
// ---------------------------------------------------------------------------
__global__ void vq_final(const unsigned int* __restrict__ counts,
                         const float* __restrict__ enorm,
                         const float* __restrict__ sum_e_d, const float* __restrict__ sum_z_d,
                         const double* __restrict__ scald, float* __restrict__ out) {
  __shared__ float sred[4];
  const int t = threadIdx.x;
  float h = 0.0f;
  for (int i = t; i < K_; i += 256) {
    const float em = (float)counts[i] * (1.0f / (float)N_);
    h += em * logf(em + 1e-10f);
  }
  const float hs = blockReduceSum(h, sred);
  __syncthreads();
  const float dv = sum_z_d[t] * sum_e_d[t];
  const float dot = blockReduceSum(dv, sred);
  __syncthreads();
  float e2 = 0.0f;
  #pragma unroll
  for (int i = 0; i < 4; ++i) e2 += enorm[t + 256 * i];
  const float sume2 = blockReduceSum(e2, sred);
  if (t == 0) {
    const double loss = (double)(1.0f + BETA_) * scald[2] / (double)((size_t)N_ * D_);
    const float perp = expf(-hs);
    const double md = scald[1] / (double)N_ + (double)sume2 / (double)K_
                    - 2.0 * (double)dot / ((double)N_ * (double)K_);
    out[OUT0 + 0] = (float)loss;
    out[OUT0 + 1] = perp;
    out[OUT0 + 2] = (float)md;
  }
}

extern "C" void kernel_launch(void* const* d_in, const int* in_sizes, int n_in,
                              void* d_out, int out_size, void* d_ws, size_t ws_size,
                              hipStream_t stream) {
  const float* z = (const float*)d_in[0];        // [32,256,32,32]
  const float* e = (const float*)d_in[1];        // [1024,256]
  float* out = (float*)d_out;

  char* ws = (char*)d_ws;
  unsigned short* E2 = (unsigned short*)(ws + E2_OFF);
  float* enorm   = (float*)(ws + ENORM_OFF);
  float* sum_e_d = (float*)(ws + SUMED_OFF);
  float* sum_z_d = (float*)(ws + SUMZD_OFF);
  unsigned int* counts = (unsigned int*)(ws + CNT_OFF);
  double* scald  = (double*)(ws + SCAL_OFF);

  hipMemsetAsync(ws + ZERO_OFF, 0x00, (size_t)ZERO_BYTES, stream);

  vq_eprep   <<<dim3(256), dim3(512), 0, stream>>>(e, z, E2, enorm, sum_e_d,
                                                   sum_z_d, scald);
  vq_argmin7 <<<dim3(512), dim3(512), 0, stream>>>(z, e, E2, enorm, out, counts,
                                                   scald);
  vq_final   <<<dim3(1),   dim3(256), 0, stream>>>(counts, enorm, sum_e_d, sum_z_d,
                                                   scald, out);
}

// Round 8
// 122.430 us; speedup vs baseline: 2.8691x; 1.1215x over previous
//
#include <hip/hip_runtime.h>
#include <stdint.h>

#define B_    32
#define D_    256
#define HW_   1024
#define N_    32768      // B_*HW_
#define K_    1024
#define BETA_ 0.25f
#define OUT0  8388608    // N_*D_

typedef short bf16x8 __attribute__((ext_vector_type(8)));
typedef unsigned int u32x4 __attribute__((ext_vector_type(4)));
typedef float f32x4  __attribute__((ext_vector_type(4)));

// ---- workspace layout (bytes) ----
#define E2_OFF    0          // 512 KB  bf16 of E, A-fragment order (k-major)
#define ENORM_OFF 524288     // 4 KB    ||e_k||^2 fp32 (exact, from fp32 e)
#define SUMED_OFF 528384     // 1 KB    col sums of E
#define SUMZD_OFF 529408     // 1 KB    per-d sums of Z
#define CNT_OFF   530432     // 4 KB    histogram
#define SCAL_OFF  534528     // 32 B    doubles: [1]=sum z^2, [2]=sum diff^2
#define ZERO_OFF  SUMED_OFF
#define ZERO_BYTES (534560 - SUMED_OFF)

__device__ __forceinline__ unsigned short f2bf(float f) {
  unsigned int u = __float_as_uint(f);
  u += 0x7FFFu + ((u >> 16) & 1u);          // round-to-nearest-even
  return (unsigned short)(u >> 16);
}

__device__ __forceinline__ unsigned long long pack64(float v, int k) {
  unsigned int b = __float_as_uint(v);
  b = (b & 0x80000000u) ? ~b : (b | 0x80000000u);   // order-preserving map
  return ((unsigned long long)b << 32) | (unsigned int)k;
}

__device__ __forceinline__ float unpack32(unsigned int p) {
  p = (p & 0x80000000u) ? (p ^ 0x80000000u) : ~p;
  return __uint_as_float(p);
}

__device__ __forceinline__ float blockReduceSum(float v, volatile float* sred) {
  #pragma unroll
  for (int off = 32; off > 0; off >>= 1) v += __shfl_down(v, off, 64);
  __syncthreads();
  if ((threadIdx.x & 63) == 0) sred[threadIdx.x >> 6] = v;
  __syncthreads();
  float r = 0.0f;
  if (threadIdx.x == 0) {
    const int nw = blockDim.x >> 6;
    for (int i = 0; i < nw; ++i) r += sred[i];
  }
  return r;  // valid on thread 0 only
}

// ---------------------------------------------------------------------------
// E prep + Z stats.  grid 256 x 512.  (unchanged from R7)
// ---------------------------------------------------------------------------
__global__ __launch_bounds__(512)
void vq_eprep(const float* __restrict__ e, const float* __restrict__ z,
              unsigned short* __restrict__ E2, float* __restrict__ enorm,
              float* __restrict__ sum_e_d, float* __restrict__ sum_z_d,
              double* __restrict__ scald) {
  __shared__ float ered[16][33];
  __shared__ float sumed[256];
  __shared__ float sred[8];
  const int t   = threadIdx.x;
  const int blk = blockIdx.x;

  if (blk < 64) {                      // ---- E-part (block-uniform branch) ----
    const int kt = blk;
    const int ds = t >> 6, l = t & 63;
    const int q  = l >> 4, m = l & 15;
    const int k  = kt * 16 + m;
    const int d0 = ds * 32 + q * 8;
    if (t < 256) sumed[t] = 0.0f;
    __syncthreads();

    const float* ep = e + (size_t)k * D_ + d0;
    const float4 v0 = *(const float4*)ep;
    const float4 v1 = *(const float4*)(ep + 4);
    const float vv[8] = {v0.x, v0.y, v0.z, v0.w, v1.x, v1.y, v1.z, v1.w};
    short hv[8];
    float p = 0.0f;
    #pragma unroll
    for (int j = 0; j < 8; ++j) {
      const float f = vv[j];
      p += f * f;
      hv[j] = (short)f2bf(f);
      float s = f;
      #pragma unroll
      for (int off = 1; off < 16; off <<= 1) s += __shfl_xor(s, off, 16);
      if ((l & 15) == 0) atomicAdd(&sumed[d0 + j], s);
    }
    const size_t fi = ((size_t)(kt * 8 + ds)) * 64 + l;
    *(bf16x8*)(E2 + fi * 8) = *(bf16x8*)hv;

    ered[m][ds * 4 + q] = p;
    __syncthreads();
    if (t < 16) {
      float s = 0.0f;
      #pragma unroll
      for (int i = 0; i < 32; ++i) s += ered[t][i];
      enorm[kt * 16 + t] = s;
    }
    if (t < 256) atomicAdd(&sum_e_d[t], sumed[t]);
  }

  // ---- Z-stats part (all blocks): 32 (b,d)-rows of 1024 floats ----
  {
    const int b  = blk >> 3;
    const int dg = (blk & 7) << 5;
    const int r  = t >> 4;             // 0..31 row within slice
    const int c  = t & 15;             // 16 lanes share a row (one quad)
    const float* zr = z + ((size_t)(b * D_ + dg + r)) * HW_;
    float s = 0.0f, s2 = 0.0f;
    #pragma unroll 4
    for (int i = 0; i < 16; ++i) {
      const float4 f = *(const float4*)(zr + i * 64 + c * 4);
      s  += (f.x + f.y) + (f.z + f.w);
      s2 += f.x * f.x + f.y * f.y + f.z * f.z + f.w * f.w;
    }
    float ssum = s;
    #pragma unroll
    for (int off = 1; off < 16; off <<= 1) ssum += __shfl_xor(ssum, off, 16);
    if (c == 0) atomicAdd(&sum_z_d[dg + r], ssum);
    const float rs2 = blockReduceSum(s2, sred);
    if (t == 0) atomicAdd(&scald[1], (double)rs2);
  }
}

// ---------------------------------------------------------------------------
// Fused argmin + gather, single-term bf16, CONFLICT-FREE LDS layout.
// R7 post-mortem: ds_read_b128 at lane-stride-16B is served phase-rigidly
// (~8-way bank alias per dword phase, ~40 cyc each; SQ_LDS_BANK_CONFLICT
// 1.48e7 = 524288 reads x 28 extra cyc).  Fix: store each B-fragment's 4
// dwords at dword-stride 5 per slot (5 coprime 32 -> every b32 access hits
// all 32 banks 2-way = free), access via 4x ds_read_b32 / ds_write_b32.
// Phase D staging re-mapped to d = c*4 + i*64 (banks r+4c+j -> 2-way free).
// Everything else identical to R7.
// ---------------------------------------------------------------------------
__global__ __launch_bounds__(512, 4)
void vq_argmin8(const float* __restrict__ z, const float* __restrict__ e,
                const unsigned short* __restrict__ E2,
                const float* __restrict__ enorm_g,
                float* __restrict__ out, unsigned int* __restrict__ counts,
                double* __restrict__ scald) {
  union SM {
    unsigned int Zs[8][1280];       // 40960 B: [ds][slot*5 + dword]
    float erow[32 * 257];           // 32896 B (epilogue staging, 32 n / pass)
  };
  __shared__ SM sm;
  __shared__ float en[1024];
  __shared__ unsigned long long red[8][64];
  __shared__ float zn2[64];
  __shared__ unsigned int kbuf[64];

  const int t  = threadIdx.x;
  const int nt = blockIdx.x;
  const int b   = nt >> 4;
  const int hw0 = (nt & 15) << 6;
  const int w = t >> 6, l = t & 63;
  const int quad = l >> 4;

  // staging identity
  const int slot  = t & 255;
  const int jh    = t >> 8;                            // 0/1 -> j = jh*4 + c
  const int squad = (slot >> 4) & 3;
  const int nloc  = ((slot >> 6) << 4) + (slot & 15);  // ni*16 + n15
  const float* zb = z + (size_t)b * D_ * HW_ + hw0 + nloc;

  if (t < 64)  zn2[t] = 0.0f;
  en[t] = enorm_g[t];
  en[t + 512] = enorm_g[t + 512];
  __syncthreads();

  // ---- Phase A: stage all of Z (single bf16, stride-5 dword layout) ----
  float zn2acc = 0.0f;
  #pragma unroll 1
  for (int ds = 0; ds < 8; ++ds) {
    const int dbase = ds * 32 + squad * 8 + jh * 4;
    float f[4];
    #pragma unroll
    for (int c = 0; c < 4; ++c) f[c] = zb[(size_t)(dbase + c) * HW_];
    #pragma unroll
    for (int c = 0; c < 4; ++c) zn2acc = fmaf(f[c], f[c], zn2acc);
    const unsigned int w0 = (unsigned int)f2bf(f[0]) | ((unsigned int)f2bf(f[1]) << 16);
    const unsigned int w1 = (unsigned int)f2bf(f[2]) | ((unsigned int)f2bf(f[3]) << 16);
    unsigned int* zp = &sm.Zs[ds][slot * 5 + jh * 2];
    zp[0] = w0;                       // banks (5*slot + 2jh + j) % 32: 2-way, free
    zp[1] = w1;
  }
  atomicAdd(&zn2[nloc], zn2acc);     // 4-way same-address only
  __syncthreads();

  // ---- Phase B/C: 4 passes of 32k x 64n, fold argmin between passes ----
  const bf16x8* __restrict__ E8 = (const bf16x8*)E2;

  float bestv[4];
  int   bestk[4];
  #pragma unroll
  for (int ni = 0; ni < 4; ++ni) { bestv[ni] = 3.0e38f; bestk[ni] = 0; }

  #pragma unroll 1
  for (int p = 0; p < 4; ++p) {
    // ktg ascending in p for each thread => first-min tiebreak holds
    const int ktg0 = ((p >> 1) << 5) + (w << 2) + ((p & 1) << 1);

    f32x4 acc[2][4];
    #pragma unroll
    for (int kti = 0; kti < 2; ++kti)
      #pragma unroll
      for (int ni = 0; ni < 4; ++ni) acc[kti][ni] = (f32x4)0.0f;

    #pragma unroll 2
    for (int ds = 0; ds < 8; ++ds) {
      bf16x8 Av[2];
      Av[0] = E8[(size_t)((ktg0 * 8) + ds) * 64 + l];
      Av[1] = E8[(size_t)((ktg0 * 8) + 8 + ds) * 64 + l];
      bf16x8 Bv[4];
      #pragma unroll
      for (int ni = 0; ni < 4; ++ni) {
        const int sb = (ni * 64 + l) * 5;
        u32x4 bw;
        bw.x = sm.Zs[ds][sb + 0];     // banks (5l + j) % 32: all 32, 2-way, free
        bw.y = sm.Zs[ds][sb + 1];
        bw.z = sm.Zs[ds][sb + 2];
        bw.w = sm.Zs[ds][sb + 3];
        Bv[ni] = __builtin_bit_cast(bf16x8, bw);
      }
      #pragma unroll
      for (int kti = 0; kti < 2; ++kti)
        #pragma unroll
        for (int ni = 0; ni < 4; ++ni)
          acc[kti][ni] = __builtin_amdgcn_mfma_f32_16x16x32_bf16(Av[kti], Bv[ni],
                                                                acc[kti][ni], 0, 0, 0);
    }
    // fold this pass (k ascending within pass as well)
    #pragma unroll
    for (int kti = 0; kti < 2; ++kti) {
      const int kb = (ktg0 + kti) * 16 + quad * 4;
      const f32x4 en4 = *(const f32x4*)&en[kb];
      #pragma unroll
      for (int ni = 0; ni < 4; ++ni) {
        const f32x4 a = acc[kti][ni];
        #pragma unroll
        for (int r = 0; r < 4; ++r) {
          const float v = fmaf(-2.0f, a[r], en4[r]);
          if (v < bestv[ni]) { bestv[ni] = v; bestk[ni] = kb + r; }
        }
      }
    }
  }

  #pragma unroll
  for (int ni = 0; ni < 4; ++ni) {
    unsigned long long p = pack64(bestv[ni], bestk[ni]);
    unsigned long long p2 = __shfl_down(p, 32, 64); if (p2 < p) p = p2;
    p2 = __shfl_down(p, 16, 64);                    if (p2 < p) p = p2;
    if (quad == 0) red[w][ni * 16 + (l & 15)] = p;
  }
  __syncthreads();   // red + zn2 ready; all Zs reads done

  if (t < 64) {
    unsigned long long m = red[0][t];
    #pragma unroll
    for (int i = 1; i < 8; ++i) { const unsigned long long c = red[i][t]; if (c < m) m = c; }
    const unsigned int k = (unsigned int)(m & 0xFFFFFFFFull);
    kbuf[t] = k;
    atomicAdd(&counts[k], 1u);
    const float dminv = unpack32((unsigned int)(m >> 32));
    float dsum = zn2[t] + dminv;     // ||z_n - e_k||^2 (analytic)
    #pragma unroll
    for (int off = 32; off > 0; off >>= 1) dsum += __shfl_down(dsum, off, 64);
    if (t == 0) atomicAdd(&scald[2], (double)dsum);
  }
  __syncthreads();   // kbuf ready; Zs dead -> erow may overwrite

  // ---- Phase D: two 32-n passes: stage chosen e-rows, write out coalesced ----
  #pragma unroll 1
  for (int p = 0; p < 2; ++p) {
    {
      const int r = t >> 4;             // 0..31 (n within pass)
      const int c = t & 15;
      const unsigned int k = kbuf[p * 32 + r];
      const float* er = e + (size_t)k * D_ + c * 4;
      #pragma unroll
      for (int i = 0; i < 4; ++i) {
        const float4 f = *(const float4*)(er + i * 64);
        float* dst = &sm.erow[r * 257 + c * 4 + i * 64];
        dst[0] = f.x; dst[1] = f.y; dst[2] = f.z; dst[3] = f.w;  // banks r+4c+j: 2-way
      }
    }
    __syncthreads();
    {
      const int s  = t >> 5;            // 0..15 -> d-slice of 16
      const int cc = t & 31;            // hw within pass
      float* ob = out + ((size_t)b * D_ + s * 16) * HW_ + hw0 + p * 32 + cc;
      #pragma unroll
      for (int i = 0; i < 16; ++i)
        ob[(size_t)i * HW_] = sm.erow[cc * 257 + s * 16 + i];
    }
    if (p == 0) __syncthreads();
  }
}

// ---------------------------------------------------------------------------
// finalize: loss, perplexity, mean_distance
// ---------------------------------------------------------------------------
__global__ void vq_final(const unsigned int* __restrict__ counts,
                         const float* __restrict__ enorm,
                         const float* __restrict__ sum_e_d, const float* __restrict__ sum_z_d,
                         const double* __restrict__ scald, float* __restrict__ out) {
  __shared__ float sred[4];
  const int t = threadIdx.x;
  float h = 0.0f;
  for (int i = t; i < K_; i += 256) {
    const float em = (float)counts[i] * (1.0f / (float)N_);
    h += em * logf(em + 1e-10f);
  }
  const float hs = blockReduceSum(h, sred);
  __syncthreads();
  const float dv = sum_z_d[t] * sum_e_d[t];
  const float dot = blockReduceSum(dv, sred);
  __syncthreads();
  float e2 = 0.0f;
  #pragma unroll
  for (int i = 0; i < 4; ++i) e2 += enorm[t + 256 * i];
  const float sume2 = blockReduceSum(e2, sred);
  if (t == 0) {
    const double loss = (double)(1.0f + BETA_) * scald[2] / (double)((size_t)N_ * D_);
    const float perp = expf(-hs);
    const double md = scald[1] / (double)N_ + (double)sume2 / (double)K_
                    - 2.0 * (double)dot / ((double)N_ * (double)K_);
    out[OUT0 + 0] = (float)loss;
    out[OUT0 + 1] = perp;
    out[OUT0 + 2] = (float)md;
  }
}

extern "C" void kernel_launch(void* const* d_in, const int* in_sizes, int n_in,
                              void* d_out, int out_size, void* d_ws, size_t ws_size,
                              hipStream_t stream) {
  const float* z = (const float*)d_in[0];        // [32,256,32,32]
  const float* e = (const float*)d_in[1];        // [1024,256]
  float* out = (float*)d_out;

  char* ws = (char*)d_ws;
  unsigned short* E2 = (unsigned short*)(ws + E2_OFF);
  float* enorm   = (float*)(ws + ENORM_OFF);
  float* sum_e_d = (float*)(ws + SUMED_OFF);
  float* sum_z_d = (float*)(ws + SUMZD_OFF);
  unsigned int* counts = (unsigned int*)(ws + CNT_OFF);
  double* scald  = (double*)(ws + SCAL_OFF);

  hipMemsetAsync(ws + ZERO_OFF, 0x00, (size_t)ZERO_BYTES, stream);

  vq_eprep   <<<dim3(256), dim3(512), 0, stream>>>(e, z, E2, enorm, sum_e_d,
                                                   sum_z_d, scald);
  vq_argmin8 <<<dim3(512), dim3(512), 0, stream>>>(z, e, E2, enorm, out, counts,
                                                   scald);
  vq_final   <<<dim3(1),   dim3(256), 0, stream>>>(counts, enorm, sum_e_d, sum_z_d,
                                                   scald, out);
}